// Round 3
// baseline (127.652 us; speedup 1.0000x reference)
//
#include <hip/hip_runtime.h>
#include <stdint.h>

// StableContrastiveLoss on MI355X (gfx950).  B=4096, D=512, C=10, T=0.07.
// Round 3: single-barrier double-buffered DMA K-loop (prefetch k+1 in flight
// across compute of k), finalize fused into sim via last-block ticket.
// 2 dispatches total.
// ws: F_bf16 [4096*512] | cls [4096] | pos_sum [4096] | all_sum [4096] | done

#define B_ROWS 4096
#define D_DIM  512
#define C_CLS  10
#define NT     32                     // 4096/128 tile-blocks per dim
#define NTILES (NT * (NT + 1) / 2)    // 528 upper-triangle tiles

typedef __bf16 bf16x8 __attribute__((ext_vector_type(8)));
typedef float  f32x4  __attribute__((ext_vector_type(4)));

// async global->LDS DMA, 16B/lane; LDS dest = wave-uniform base + lane*16
__device__ __forceinline__ void load_lds16(const __bf16* g, __bf16* l) {
  __builtin_amdgcn_global_load_lds(
      (const __attribute__((address_space(1))) unsigned int*)g,
      (__attribute__((address_space(3))) unsigned int*)l, 16, 0, 0);
}

// ---------------- Kernel 1: normalize rows + class extract + zero accum ----
__global__ __launch_bounds__(256) void prep_kernel(
    const float* __restrict__ feats, const float* __restrict__ labels,
    __bf16* __restrict__ F, int* __restrict__ cls,
    float* __restrict__ pos_sum, float* __restrict__ all_sum,
    int* __restrict__ done) {
  const int w = threadIdx.x >> 6, lane = threadIdx.x & 63;
  const int row = blockIdx.x * 4 + w;   // one wave per row
  const float* fr = feats + (size_t)row * D_DIM;
  float4 v0 = ((const float4*)fr)[2 * lane];
  float4 v1 = ((const float4*)fr)[2 * lane + 1];
  float ss = v0.x*v0.x + v0.y*v0.y + v0.z*v0.z + v0.w*v0.w
           + v1.x*v1.x + v1.y*v1.y + v1.z*v1.z + v1.w*v1.w;
  #pragma unroll
  for (int m = 1; m < 64; m <<= 1) ss += __shfl_xor(ss, m, 64);
  float inv = 1.0f / sqrtf(ss);

  bf16x8 o;
  o[0] = (__bf16)(v0.x * inv); o[1] = (__bf16)(v0.y * inv);
  o[2] = (__bf16)(v0.z * inv); o[3] = (__bf16)(v0.w * inv);
  o[4] = (__bf16)(v1.x * inv); o[5] = (__bf16)(v1.y * inv);
  o[6] = (__bf16)(v1.z * inv); o[7] = (__bf16)(v1.w * inv);
  *(bf16x8*)(F + (size_t)row * D_DIM + 8 * lane) = o;

  float lv = (lane < C_CLS) ? labels[(size_t)row * C_CLS + lane] : 0.f;
  unsigned long long m = __ballot(lv > 0.5f);
  if (lane == 0) {
    cls[row] = (int)(__ffsll((long long)m) - 1);
    pos_sum[row] = 0.f;
    all_sum[row] = 0.f;
  }
  if (blockIdx.x == 0 && threadIdx.x == 0) *done = 0;
}

// ------- Kernel 2: symmetric sim + exp + row/col sums + fused finalize -----
__global__ __launch_bounds__(256) void sim_kernel(
    const __bf16* __restrict__ F, const int* __restrict__ cls,
    float* __restrict__ pos_sum, float* __restrict__ all_sum,
    int* __restrict__ done, float* __restrict__ out) {
  __shared__ __align__(16) __bf16 Abuf[2][128 * 64];
  __shared__ __align__(16) __bf16 Bbuf[2][128 * 64];
  __shared__ int clsA[128], clsB[128];
  __shared__ int ticket_s;
  __shared__ float redv[8];

  // triangular tile decode (block-uniform)
  int rem = blockIdx.x, bi = 0, rowlen = NT;
  while (rem >= rowlen) { rem -= rowlen; ++bi; --rowlen; }
  const int bj = bi + rem;
  const int i0 = bi * 128, j0 = bj * 128;
  const bool offdiag = (bi != bj);

  const int tid = threadIdx.x;
  const int w = tid >> 6, lane = tid & 63;
  const int wi = w & 1, wj = w >> 1;       // 2x2 wave grid over 128x128
  const int q = lane >> 4, cl = lane & 15;

  if (tid < 128) clsA[tid] = cls[i0 + tid];
  else           clsB[tid - 128] = cls[j0 + tid - 128];

  f32x4 acc[4][4];
  #pragma unroll
  for (int ri = 0; ri < 4; ++ri)
    #pragma unroll
    for (int cj = 0; cj < 4; ++cj) acc[ri][cj] = (f32x4){0.f, 0.f, 0.f, 0.f};

  // staging roles: lane L -> subrow L/8, LDS chunk L%8 holds global chunk
  // (L%8)^(row%8)  => conflict-distributed b128 reads
  const int srow = lane >> 3;
  const int sg   = (lane & 7) ^ srow;

  #define STAGE(k0, b)                                                        \
    _Pragma("unroll")                                                         \
    for (int r = 0; r < 4; ++r) {                                             \
      const int rowbase = w * 32 + r * 8;                                     \
      const __bf16* ga = F + (size_t)(i0 + rowbase + srow) * D_DIM + (k0) + sg * 8; \
      const __bf16* gb = F + (size_t)(j0 + rowbase + srow) * D_DIM + (k0) + sg * 8; \
      load_lds16(ga, &Abuf[b][rowbase * 64]);                                 \
      load_lds16(gb, &Bbuf[b][rowbase * 64]);                                 \
    }

  STAGE(0, 0)

  #pragma unroll
  for (int k = 0; k < D_DIM / 64; ++k) {
    __syncthreads();   // drains DMA(k); buf[(k+1)&1] readers finished earlier
    if (k < D_DIM / 64 - 1) { STAGE((k + 1) * 64, (k + 1) & 1) }
    const __bf16* Ab = &Abuf[k & 1][0];
    const __bf16* Bb = &Bbuf[k & 1][0];
    #pragma unroll
    for (int kk = 0; kk < 64; kk += 32) {
      const int cc = ((kk >> 3) + q) ^ (cl & 7);  // swizzled LDS chunk
      bf16x8 af[4], bf[4];
      #pragma unroll
      for (int ri = 0; ri < 4; ++ri)
        af[ri] = *(const bf16x8*)&Ab[(64 * wi + 16 * ri + cl) * 64 + cc * 8];
      #pragma unroll
      for (int cj = 0; cj < 4; ++cj)
        bf[cj] = *(const bf16x8*)&Bb[(64 * wj + 16 * cj + cl) * 64 + cc * 8];
      #pragma unroll
      for (int ri = 0; ri < 4; ++ri)
        #pragma unroll
        for (int cj = 0; cj < 4; ++cj)
          acc[ri][cj] = __builtin_amdgcn_mfma_f32_16x16x32_bf16(
              af[ri], bf[cj], acc[ri][cj], 0, 0, 0);
    }
  }
  #undef STAGE

  // Epilogue. D layout: col = lane&15 (j), row = q*4 + reg (i).
  const float invT = 1.0f / 0.07f;
  float cs_all[4] = {0.f, 0.f, 0.f, 0.f};
  float cs_pos[4] = {0.f, 0.f, 0.f, 0.f};

  #pragma unroll
  for (int ri = 0; ri < 4; ++ri) {
    float ra[4] = {0.f, 0.f, 0.f, 0.f};
    float rp[4] = {0.f, 0.f, 0.f, 0.f};
    #pragma unroll
    for (int cj = 0; cj < 4; ++cj) {
      const int jloc = 64 * wj + 16 * cj + cl;
      const int gj = j0 + jloc;
      const int cjc = clsB[jloc];
      #pragma unroll
      for (int r = 0; r < 4; ++r) {
        const int iloc = 64 * wi + 16 * ri + q * 4 + r;
        const int gi = i0 + iloc;
        float s = acc[ri][cj][r] * invT;
        s = fminf(fmaxf(s, -20.f), 20.f);
        const bool diag = (gi == gj);
        float e = diag ? 0.f : __expf(s);
        ra[r] += e;
        cs_all[cj] += e;
        if (!diag && cjc == clsA[iloc]) { rp[r] += e; cs_pos[cj] += e; }
      }
    }
    #pragma unroll
    for (int r = 0; r < 4; ++r) {
      float sa = ra[r], sp = rp[r];
      #pragma unroll
      for (int m = 1; m < 16; m <<= 1) {
        sa += __shfl_xor(sa, m, 64);
        sp += __shfl_xor(sp, m, 64);
      }
      if (cl == 0) {
        const int gi = i0 + 64 * wi + 16 * ri + q * 4 + r;
        atomicAdd(&all_sum[gi], sa);
        atomicAdd(&pos_sum[gi], sp);
      }
    }
  }
  if (offdiag) {   // symmetry: column sums feed rows j
    #pragma unroll
    for (int cj = 0; cj < 4; ++cj) {
      float sa = cs_all[cj], sp = cs_pos[cj];
      sa += __shfl_xor(sa, 16, 64); sa += __shfl_xor(sa, 32, 64);
      sp += __shfl_xor(sp, 16, 64); sp += __shfl_xor(sp, 32, 64);
      if (q == 0) {
        const int gj = j0 + 64 * wj + 16 * cj + cl;
        atomicAdd(&all_sum[gj], sa);
        atomicAdd(&pos_sum[gj], sp);
      }
    }
  }

  // ---- fused finalize: last block to finish reduces the loss ----
  __threadfence();           // release our atomics before taking a ticket
  __syncthreads();
  if (tid == 0) ticket_s = atomicAdd(done, 1);
  __syncthreads();
  if (ticket_s == NTILES - 1) {   // block-uniform
    __threadfence();         // acquire all other blocks' sums
    float total = 0.f, cnt = 0.f;
    for (int i = tid; i < B_ROWS; i += 256) {
      float ps = pos_sum[i], as = all_sum[i];
      if (ps > 0.f) {        // valid iff >=1 positive (exp > 0 always)
        total += -__logf(ps / (as + 1e-8f) + 1e-8f);
        cnt += 1.f;
      }
    }
    #pragma unroll
    for (int m = 1; m < 64; m <<= 1) {
      total += __shfl_xor(total, m, 64);
      cnt   += __shfl_xor(cnt, m, 64);
    }
    if ((tid & 63) == 0) { redv[tid >> 6] = total; redv[4 + (tid >> 6)] = cnt; }
    __syncthreads();
    if (tid == 0) {
      float T = 0.f, Cn = 0.f;
      #pragma unroll
      for (int i = 0; i < 4; ++i) { T += redv[i]; Cn += redv[4 + i]; }
      out[0] = (Cn > 0.f) ? (T / Cn) : 0.f;
    }
  }
}

extern "C" void kernel_launch(void* const* d_in, const int* in_sizes, int n_in,
                              void* d_out, int out_size, void* d_ws, size_t ws_size,
                              hipStream_t stream) {
  const float* features = (const float*)d_in[0];
  const float* labels   = (const float*)d_in[1];
  float* out = (float*)d_out;

  __bf16* F       = (__bf16*)d_ws;
  int*    cls     = (int*)((char*)d_ws + (size_t)B_ROWS * D_DIM * 2);
  float*  pos_sum = (float*)((char*)cls + B_ROWS * sizeof(int));
  float*  all_sum = pos_sum + B_ROWS;
  int*    done    = (int*)(all_sum + B_ROWS);

  prep_kernel<<<B_ROWS / 4, 256, 0, stream>>>(features, labels, F, cls,
                                              pos_sum, all_sum, done);
  sim_kernel<<<NTILES, 256, 0, stream>>>(F, cls, pos_sum, all_sum, done, out);
}